// Round 3
// baseline (678.685 us; speedup 1.0000x reference)
//
#include <hip/hip_runtime.h>
#include <hip/hip_bf16.h>

typedef unsigned int uint;
typedef unsigned short ushort;
typedef __attribute__((ext_vector_type(8))) short bf16x8;
typedef __attribute__((ext_vector_type(4))) float f32x4;

__device__ __forceinline__ float bf2f(ushort u) {
    return __uint_as_float(((uint)u) << 16);
}
__device__ __forceinline__ ushort f2bf(float f) {
    uint u = __float_as_uint(f);
    u += 0x7FFFu + ((u >> 16) & 1u);   // round-to-nearest-even
    return (ushort)(u >> 16);
}
__device__ __forceinline__ uint cvtpk(float lo, float hi) {
    uint r;
    asm("v_cvt_pk_bf16_f32 %0, %1, %2" : "=v"(r) : "v"(lo), "v"(hi));
    return r;
}
__device__ __forceinline__ float sigm(float x) {
    return 1.0f / (1.0f + expf(-x));
}

// ---------------- kernel 1: P[v][g] = tanh(emb[v]) @ w_ih^T + b_ih  [96,512]
__global__ void kP(const float* __restrict__ emb, const float* __restrict__ w_ih,
                   const float* __restrict__ b_ih, float* __restrict__ P)
{
    __shared__ __align__(16) float te[300];
    int v = blockIdx.x, tid = threadIdx.x;          // block 512
    for (int k = tid; k < 300; k += 512) te[k] = tanhf(emb[v * 300 + k]);
    __syncthreads();
    int g = tid;
    float acc = b_ih[g];
    const float4* wr = (const float4*)(w_ih + g * 300);
    const float4* tv = (const float4*)te;
    for (int k = 0; k < 75; ++k) {
        float4 w4 = wr[k], t4 = tv[k];
        acc += w4.x * t4.x + w4.y * t4.y + w4.z * t4.z + w4.w * t4.w;
    }
    P[v * 512 + g] = acc;
}

// ---------------- kernel 2: Wst chunks [li][kc][col][kk] (plain layout)
__global__ void kW(const float* __restrict__ g_w2, const float* __restrict__ g_w3,
                   const float* __restrict__ g_w4, ushort* __restrict__ Wst)
{
    int li = blockIdx.x >> 3, kc = blockIdx.x & 7, col = threadIdx.x;  // block 256
    const float* W = (li == 0) ? g_w2 : (li == 1) ? g_w3 : g_w4;
    ushort* dst = Wst + li * 65536 + kc * 8192;
    for (int kk = 0; kk < 32; ++kk)
        dst[col * 32 + kk] = f2bf(W[(kc * 32 + kk) * 256 + col]);
}

// ---------------- kernel 3: LSTM (final cell state) -> Wq[b] = c@W1c + g_b1
__global__ void kLSTM(const float* __restrict__ P, const float* __restrict__ w_hh,
                      const float* __restrict__ b_hh, const float* __restrict__ g_w1,
                      const float* __restrict__ g_b1, const int* __restrict__ q_feats,
                      const int* __restrict__ q_lens, float* __restrict__ Wq)
{
    __shared__ __align__(16) float h[128];
    __shared__ __align__(16) float c[128];
    __shared__ float gates[512];
    int b = blockIdx.x, tid = threadIdx.x;          // block 256
    if (tid < 128) { h[tid] = 0.f; c[tid] = 0.f; }
    __syncthreads();
    int len = q_lens[b];
    for (int t = 0; t < 20; ++t) {
        int idx = q_feats[b * 20 + t];
        for (int g = tid; g < 512; g += 256) {
            float acc = P[idx * 512 + g] + b_hh[g];
            const float4* wr = (const float4*)(w_hh + g * 128);
            const float4* hv = (const float4*)h;
            #pragma unroll 8
            for (int k = 0; k < 32; ++k) {
                float4 w4 = wr[k], h4 = hv[k];
                acc += w4.x * h4.x + w4.y * h4.y + w4.z * h4.z + w4.w * h4.w;
            }
            gates[g] = acc;
        }
        __syncthreads();
        if (tid < 128 && t < len) {
            float ig = sigm(gates[tid]);
            float fg = sigm(gates[128 + tid]);
            float gg = tanhf(gates[256 + tid]);
            float og = sigm(gates[384 + tid]);
            float cn = fg * c[tid] + ig * gg;
            c[tid] = cn;
            h[tid] = og * tanhf(cn);
        }
        __syncthreads();
    }
    int l = tid;
    float acc = g_b1[l];
    for (int k = 0; k < 128; ++k) acc += c[k] * g_w1[(52 + k) * 256 + l];
    Wq[b * 256 + l] = acc;
}

// ---------------- kernel 4: A1/A2 layer-1 partials, one block per b
__global__ __launch_bounds__(256) void kA(
    const float* __restrict__ box_feats, const float* __restrict__ g_w1,
    const float* __restrict__ Wq, ushort* __restrict__ A1, ushort* __restrict__ A2)
{
    __shared__ float box[64][26];
    __shared__ float wq[256];
    int b = blockIdx.x, tid = threadIdx.x;           // block 256
    for (int idx = tid; idx < 64 * 26; idx += 256) {
        int n = idx / 26, d = idx - n * 26;
        float v;
        if (d < 24)       v = box_feats[(b * 64 + n) * 24 + d];
        else if (d == 24) v = ((n >> 3) - 4) * 0.125f;
        else              v = ((n & 7) - 4) * 0.125f;
        box[n][d] = v;
    }
    wq[tid] = Wq[b * 256 + tid];
    __syncthreads();
    float w1a[26], w1b[26];
    #pragma unroll
    for (int d = 0; d < 26; ++d) {
        w1a[d] = g_w1[d * 256 + tid];
        w1b[d] = g_w1[(26 + d) * 256 + tid];
    }
    for (int n = 0; n < 64; ++n) {
        float a1 = 0.f, a2 = wq[tid];
        #pragma unroll
        for (int d = 0; d < 26; ++d) {
            a1 += box[n][d] * w1a[d];
            a2 += box[n][d] * w1b[d];
        }
        A1[(b * 64 + n) * 256 + tid] = f2bf(a1);
        A2[(b * 64 + n) * 256 + tid] = f2bf(a2);
    }
}

// ---------------- kernel 5: fused pair-MLP (layers 2-4), raw-barrier counted-wait
__global__ __launch_bounds__(256, 2) void kD(
    const ushort* __restrict__ A1, const ushort* __restrict__ A2,
    const ushort* __restrict__ Wst,
    const float* __restrict__ b2, const float* __restrict__ b3,
    const float* __restrict__ b4, float* __restrict__ partial)
{
    __shared__ __align__(16) ushort lds_x[128 * 256];   // 65536 B, XOR-swizzled rows
    __shared__ __align__(16) ushort lds_w[8192];        // 16384 B, one W k-chunk

    const int tid = threadIdx.x;
    const int b = blockIdx.x >> 5, iblk = blockIdx.x & 31;   // 2 pairs: i = iblk*2 + p
    const int lane = tid & 63, wv = tid >> 6;
    const int l15 = lane & 15, lg = lane >> 4;
    const int row0 = (wv & 1) * 64, col0 = (wv >> 1) * 128;  // wave tile: 64r x 128c

    const uint4* wsrc = (const uint4*)Wst;
    uint4* wdst = (uint4*)lds_w;

    // prefetch W chunk q=0 into regs (issue-early; lands during X-build)
    uint4 wbuf[4];
    #pragma unroll
    for (int g = 0; g < 4; ++g) wbuf[g] = wsrc[tid * 4 + g];

    // ---- build X1 (swizzled): X1[p*64+j][l] = relu(A1[i0+p][l] + A2[b,j][l])
    float* a1s = (float*)lds_w;    // alias; consumed before first W ds_write
    a1s[tid]       = bf2f(A1[(b * 64 + iblk * 2    ) * 256 + tid]);
    a1s[256 + tid] = bf2f(A1[(b * 64 + iblk * 2 + 1) * 256 + tid]);
    __syncthreads();
    const ushort* A2b = A2 + b * 64 * 256;
    #pragma unroll
    for (int p8 = 0; p8 < 16; ++p8) {
        int task = p8 * 256 + tid;
        int row = task >> 5, l0 = (task & 31) << 3;
        int j = row & 63, pr = row >> 6;
        uint4 v = *(const uint4*)(A2b + j * 256 + l0);
        const float* av = a1s + pr * 256 + l0;
        uint vv[4] = {v.x, v.y, v.z, v.w}, ov[4];
        #pragma unroll
        for (int q = 0; q < 4; ++q) {
            float f0 = av[2 * q]     + bf2f((ushort)(vv[q] & 0xFFFFu));
            float f1 = av[2 * q + 1] + bf2f((ushort)(vv[q] >> 16));
            ov[q] = cvtpk(fmaxf(f0, 0.f), fmaxf(f1, 0.f));
        }
        *(uint4*)&lds_x[row * 256 + (l0 ^ ((row & 7) << 3))] =
            make_uint4(ov[0], ov[1], ov[2], ov[3]);
    }
    __syncthreads();   // X ready; a1s fully consumed -> lds_w free

    int q = 0;   // linear chunk index li*8+kc
    #pragma unroll 1
    for (int li = 0; li < 3; ++li) {
        const float* bias = (li == 0) ? b2 : (li == 1) ? b3 : b4;
        f32x4 acc[4][8];
        #pragma unroll
        for (int ct = 0; ct < 8; ++ct) {
            f32x4 bv = *(const f32x4*)(bias + col0 + ct * 16 + lg * 4);
            #pragma unroll
            for (int rt = 0; rt < 4; ++rt) acc[rt][ct] = bv;
        }
        #pragma unroll 1
        for (int kc = 0; kc < 8; ++kc) {
            // ---- bar1: W buffer free (prev chunk's reads all consumed by MFMAs)
            __builtin_amdgcn_s_barrier();
            asm volatile("s_waitcnt vmcnt(0)" ::: "memory");   // wbuf regs landed
            __builtin_amdgcn_sched_barrier(0);
            #pragma unroll
            for (int g = 0; g < 4; ++g) wdst[tid * 4 + g] = wbuf[g];
            if (q < 23) {
                const uint4* src = wsrc + (q + 1) * 1024;      // next 16KB chunk
                #pragma unroll
                for (int g = 0; g < 4; ++g) wbuf[g] = src[tid * 4 + g];
            }
            asm volatile("s_waitcnt lgkmcnt(0)" ::: "memory"); // ds_writes visible
            __builtin_amdgcn_sched_barrier(0);
            // ---- bar2: W buffer ready; global prefetch stays in flight
            __builtin_amdgcn_s_barrier();

            bf16x8 xb[4];
            #pragma unroll
            for (int rt = 0; rt < 4; ++rt) {
                int row = row0 + rt * 16 + l15;
                xb[rt] = *(const bf16x8*)
                    &lds_x[row * 256 + ((kc * 32 + lg * 8) ^ ((row & 7) << 3))];
            }
            __builtin_amdgcn_s_setprio(1);
            #pragma unroll
            for (int ct = 0; ct < 8; ++ct) {
                int col = col0 + ct * 16 + l15;
                bf16x8 wa = *(const bf16x8*)&lds_w[col * 32 + lg * 8];
                #pragma unroll
                for (int rt = 0; rt < 4; ++rt)
                    acc[rt][ct] = __builtin_amdgcn_mfma_f32_16x16x32_bf16(
                        wa, xb[rt], acc[rt][ct], 0, 0, 0);
            }
            __builtin_amdgcn_s_setprio(0);
            ++q;
        }
        if (li < 2) {
            // all waves' X reads for this layer are consumed -> safe to overwrite
            __builtin_amdgcn_s_barrier();
            #pragma unroll
            for (int rt = 0; rt < 4; ++rt) {
                int row = row0 + rt * 16 + l15;
                int sw = (row & 7) << 3;
                #pragma unroll
                for (int ct = 0; ct < 8; ++ct) {
                    f32x4 a = acc[rt][ct];
                    uint2 pk;
                    pk.x = cvtpk(fmaxf(a[0], 0.f), fmaxf(a[1], 0.f));
                    pk.y = cvtpk(fmaxf(a[2], 0.f), fmaxf(a[3], 0.f));
                    *(uint2*)&lds_x[row * 256 + ((col0 + ct * 16 + lg * 4) ^ sw)] = pk;
                }
            }
            // writeback ds_writes are drained by next iteration's lgkmcnt(0)
            // before bar2, ahead of any reader's xb read.
        } else {
            // reduce over this wave's 64 rows (pair p = wv&1), deterministic
            #pragma unroll
            for (int ct = 0; ct < 8; ++ct) {
                f32x4 s = {0.f, 0.f, 0.f, 0.f};
                #pragma unroll
                for (int rt = 0; rt < 4; ++rt) {
                    f32x4 a = acc[rt][ct];
                    s[0] += fmaxf(a[0], 0.f); s[1] += fmaxf(a[1], 0.f);
                    s[2] += fmaxf(a[2], 0.f); s[3] += fmaxf(a[3], 0.f);
                }
                #pragma unroll
                for (int m = 1; m < 16; m <<= 1) {
                    s[0] += __shfl_xor(s[0], m, 64);
                    s[1] += __shfl_xor(s[1], m, 64);
                    s[2] += __shfl_xor(s[2], m, 64);
                    s[3] += __shfl_xor(s[3], m, 64);
                }
                if (l15 == 0) {
                    float4 o = {s[0], s[1], s[2], s[3]};
                    *(float4*)&partial[(b * 64 + iblk * 2 + (wv & 1)) * 256
                                       + col0 + ct * 16 + lg * 4] = o;
                }
            }
        }
    }
}

// ---------------- kernel 6: g_out[b][col] = sum_i partial[(b,i)][col]
__global__ void kR(const float* __restrict__ partial, float* __restrict__ gout)
{
    int b = blockIdx.x, col = threadIdx.x;     // block 256
    float s = 0.f;
    for (int i = 0; i < 64; ++i) s += partial[(b * 64 + i) * 256 + col];
    gout[b * 256 + col] = s;
}

// ---------------- kernel 7: f-network
__global__ void kF(const float* __restrict__ gout,
                   const float* __restrict__ f_w1, const float* __restrict__ f_b1,
                   const float* __restrict__ f_w2, const float* __restrict__ f_b2,
                   const float* __restrict__ f_w3, const float* __restrict__ f_b3,
                   float* __restrict__ out)
{
    __shared__ float g[256], y1[256], y2[256];
    int b = blockIdx.x, t = threadIdx.x;       // block 256
    g[t] = gout[b * 256 + t];
    __syncthreads();
    float acc = f_b1[t];
    for (int k = 0; k < 256; ++k) acc += g[k] * f_w1[k * 256 + t];
    y1[t] = fmaxf(acc, 0.f);
    __syncthreads();
    acc = f_b2[t];
    for (int k = 0; k < 256; ++k) acc += y1[k] * f_w2[k * 256 + t];
    y2[t] = fmaxf(acc, 0.f);
    __syncthreads();
    if (t < 100) {
        float o = f_b3[t];
        for (int k = 0; k < 256; ++k) o += y2[k] * f_w3[k * 100 + t];
        out[b * 100 + t] = o;
    }
}

extern "C" void kernel_launch(void* const* d_in, const int* in_sizes, int n_in,
                              void* d_out, int out_size, void* d_ws, size_t ws_size,
                              hipStream_t stream)
{
    const float* box_feats = (const float*)d_in[0];
    const float* emb   = (const float*)d_in[1];
    const float* w_ih  = (const float*)d_in[2];
    const float* w_hh  = (const float*)d_in[3];
    const float* b_ih  = (const float*)d_in[4];
    const float* b_hh  = (const float*)d_in[5];
    const float* g_w1  = (const float*)d_in[6];
    const float* g_b1  = (const float*)d_in[7];
    const float* g_w2  = (const float*)d_in[8];
    const float* g_b2  = (const float*)d_in[9];
    const float* g_w3  = (const float*)d_in[10];
    const float* g_b3  = (const float*)d_in[11];
    const float* g_w4  = (const float*)d_in[12];
    const float* g_b4  = (const float*)d_in[13];
    const float* f_w1  = (const float*)d_in[14];
    const float* f_b1  = (const float*)d_in[15];
    const float* f_w2  = (const float*)d_in[16];
    const float* f_b2  = (const float*)d_in[17];
    const float* f_w3  = (const float*)d_in[18];
    const float* f_b3  = (const float*)d_in[19];
    const int* q_feats = (const int*)d_in[20];
    const int* q_lens  = (const int*)d_in[21];
    float* out = (float*)d_out;

    char* ws = (char*)d_ws;
    float*  P    = (float*) (ws + 0);          //  96*512*4      = 196608
    float*  Wq   = (float*) (ws + 196608);     // 128*256*4      = 131072
    ushort* A1   = (ushort*)(ws + 327680);     // 8192*256*2     = 4194304
    ushort* A2   = (ushort*)(ws + 4521984);    // 8192*256*2     = 4194304
    ushort* Wst  = (ushort*)(ws + 8716288);    // 3*65536*2      = 393216
    float*  part = (float*) (ws + 9109504);    // 8192*256*4     = 8388608
    float*  gout = (float*) (ws + 17498112);   // 128*256*4      = 131072

    hipLaunchKernelGGL(kP,    dim3(96),   dim3(512), 0, stream, emb, w_ih, b_ih, P);
    hipLaunchKernelGGL(kW,    dim3(24),   dim3(256), 0, stream, g_w2, g_w3, g_w4, Wst);
    hipLaunchKernelGGL(kLSTM, dim3(128),  dim3(256), 0, stream, P, w_hh, b_hh, g_w1, g_b1, q_feats, q_lens, Wq);
    hipLaunchKernelGGL(kA,    dim3(128),  dim3(256), 0, stream, box_feats, g_w1, Wq, A1, A2);
    hipLaunchKernelGGL(kD,    dim3(4096), dim3(256), 0, stream, A1, A2, Wst, g_b2, g_b3, g_b4, part);
    hipLaunchKernelGGL(kR,    dim3(128),  dim3(256), 0, stream, part, gout);
    hipLaunchKernelGGL(kF,    dim3(128),  dim3(256), 0, stream, gout, f_w1, f_b1, f_w2, f_b2, f_w3, f_b3, out);
}

// Round 4
// 453.469 us; speedup vs baseline: 1.4967x; 1.4967x over previous
//
#include <hip/hip_runtime.h>
#include <hip/hip_bf16.h>

typedef unsigned int uint;
typedef unsigned short ushort;
typedef __attribute__((ext_vector_type(8))) short bf16x8;
typedef __attribute__((ext_vector_type(4))) float f32x4;

__device__ __forceinline__ float bf2f(ushort u) {
    return __uint_as_float(((uint)u) << 16);
}
__device__ __forceinline__ ushort f2bf(float f) {
    uint u = __float_as_uint(f);
    u += 0x7FFFu + ((u >> 16) & 1u);   // round-to-nearest-even
    return (ushort)(u >> 16);
}
__device__ __forceinline__ uint cvtpk(float lo, float hi) {
    uint r;
    asm("v_cvt_pk_bf16_f32 %0, %1, %2" : "=v"(r) : "v"(lo), "v"(hi));
    return r;
}
__device__ __forceinline__ float sigm(float x) {
    return 1.0f / (1.0f + expf(-x));
}

// ---------------- kernel 1: P[v][g] = tanh(emb[v]) @ w_ih^T + b_ih  [96,512]
__global__ void kP(const float* __restrict__ emb, const float* __restrict__ w_ih,
                   const float* __restrict__ b_ih, float* __restrict__ P)
{
    __shared__ __align__(16) float te[300];
    int v = blockIdx.x, tid = threadIdx.x;          // block 512
    for (int k = tid; k < 300; k += 512) te[k] = tanhf(emb[v * 300 + k]);
    __syncthreads();
    int g = tid;
    float acc = b_ih[g];
    const float4* wr = (const float4*)(w_ih + g * 300);
    const float4* tv = (const float4*)te;
    for (int k = 0; k < 75; ++k) {
        float4 w4 = wr[k], t4 = tv[k];
        acc += w4.x * t4.x + w4.y * t4.y + w4.z * t4.z + w4.w * t4.w;
    }
    P[v * 512 + g] = acc;
}

// ---------------- kernel 2: Wst chunks [li][kc][col][slot], bank-swizzle baked
__global__ void kW(const float* __restrict__ g_w2, const float* __restrict__ g_w3,
                   const float* __restrict__ g_w4, ushort* __restrict__ Wst)
{
    int li = blockIdx.x >> 3, kc = blockIdx.x & 7, col = threadIdx.x;  // block 256
    const float* W = (li == 0) ? g_w2 : (li == 1) ? g_w3 : g_w4;
    ushort* dst = Wst + li * 65536 + kc * 8192;
    for (int kk = 0; kk < 32; ++kk) {
        int slot = (kk >> 3) ^ ((col >> 1) & 3);   // 2-way-free on b128 reads
        dst[col * 32 + slot * 8 + (kk & 7)] = f2bf(W[(kc * 32 + kk) * 256 + col]);
    }
}

// ---------------- kernel 3: LSTM (final cell state) -> Wq[b] = c@W1c + g_b1
__global__ void kLSTM(const float* __restrict__ P, const float* __restrict__ w_hh,
                      const float* __restrict__ b_hh, const float* __restrict__ g_w1,
                      const float* __restrict__ g_b1, const int* __restrict__ q_feats,
                      const int* __restrict__ q_lens, float* __restrict__ Wq)
{
    __shared__ __align__(16) float h[128];
    __shared__ __align__(16) float c[128];
    __shared__ float gates[512];
    int b = blockIdx.x, tid = threadIdx.x;          // block 256
    if (tid < 128) { h[tid] = 0.f; c[tid] = 0.f; }
    __syncthreads();
    int len = q_lens[b];
    for (int t = 0; t < 20; ++t) {
        int idx = q_feats[b * 20 + t];
        for (int g = tid; g < 512; g += 256) {
            float acc = P[idx * 512 + g] + b_hh[g];
            const float4* wr = (const float4*)(w_hh + g * 128);
            const float4* hv = (const float4*)h;
            #pragma unroll 8
            for (int k = 0; k < 32; ++k) {
                float4 w4 = wr[k], h4 = hv[k];
                acc += w4.x * h4.x + w4.y * h4.y + w4.z * h4.z + w4.w * h4.w;
            }
            gates[g] = acc;
        }
        __syncthreads();
        if (tid < 128 && t < len) {
            float ig = sigm(gates[tid]);
            float fg = sigm(gates[128 + tid]);
            float gg = tanhf(gates[256 + tid]);
            float og = sigm(gates[384 + tid]);
            float cn = fg * c[tid] + ig * gg;
            c[tid] = cn;
            h[tid] = og * tanhf(cn);
        }
        __syncthreads();
    }
    int l = tid;
    float acc = g_b1[l];
    for (int k = 0; k < 128; ++k) acc += c[k] * g_w1[(52 + k) * 256 + l];
    Wq[b * 256 + l] = acc;
}

// ---------------- kernel 4: A1/A2 layer-1 partials, one block per b
__global__ __launch_bounds__(256) void kA(
    const float* __restrict__ box_feats, const float* __restrict__ g_w1,
    const float* __restrict__ Wq, ushort* __restrict__ A1, ushort* __restrict__ A2)
{
    __shared__ float box[64][26];
    __shared__ float wq[256];
    int b = blockIdx.x, tid = threadIdx.x;           // block 256
    for (int idx = tid; idx < 64 * 26; idx += 256) {
        int n = idx / 26, d = idx - n * 26;
        float v;
        if (d < 24)       v = box_feats[(b * 64 + n) * 24 + d];
        else if (d == 24) v = ((n >> 3) - 4) * 0.125f;
        else              v = ((n & 7) - 4) * 0.125f;
        box[n][d] = v;
    }
    wq[tid] = Wq[b * 256 + tid];
    __syncthreads();
    float w1a[26], w1b[26];
    #pragma unroll
    for (int d = 0; d < 26; ++d) {
        w1a[d] = g_w1[d * 256 + tid];
        w1b[d] = g_w1[(26 + d) * 256 + tid];
    }
    for (int n = 0; n < 64; ++n) {
        float a1 = 0.f, a2 = wq[tid];
        #pragma unroll
        for (int d = 0; d < 26; ++d) {
            a1 += box[n][d] * w1a[d];
            a2 += box[n][d] * w1b[d];
        }
        A1[(b * 64 + n) * 256 + tid] = f2bf(a1);
        A2[(b * 64 + n) * 256 + tid] = f2bf(a2);
    }
}

// ---------------- kernel 5: fused pair-MLP, 256 rows/block, W dbuf, 1 barrier/chunk
__global__ __launch_bounds__(512, 2) void kD(
    const ushort* __restrict__ A1, const ushort* __restrict__ A2,
    const ushort* __restrict__ Wst,
    const float* __restrict__ b2, const float* __restrict__ b3,
    const float* __restrict__ b4, float* __restrict__ partial)
{
    __shared__ __align__(16) ushort lds_x[256 * 256];   // 131072 B, XOR-swizzled rows
    __shared__ __align__(16) ushort lds_w[2][8192];     // 2 x 16384 B (dbuf) -> 160KB total

    const int tid = threadIdx.x;
    const int b = blockIdx.x >> 4, iblk = blockIdx.x & 15;   // 4 pairs: i = iblk*4+p
    const int lane = tid & 63, wv = tid >> 6;                // 8 waves
    const int l15 = lane & 15, lg = lane >> 4;
    const int wrow0 = (wv & 1) * 128, col0 = (wv >> 1) * 64; // wave tile 128r x 64c

    const uint4* wsrc = (const uint4*)Wst;   // 24 chunks x 1024 uint4, swizzle baked

    // issue W chunk-0 prefetch FIRST (lands during X-build; raw barriers keep it in flight)
    uint4 rbuf0 = wsrc[tid];
    uint4 rbuf1 = wsrc[512 + tid];

    // ---- stage 4 A1 rows as f32 (alias in lds_w[0]; consumed before wbuf[0] write)
    float* a1s = (float*)lds_w;    // 4 x 256 floats = 4KB
    {
        int p = tid >> 8, l = tid & 255;
        a1s[tid]       = bf2f(A1[(b * 64 + iblk * 4 + p)     * 256 + l]);
        a1s[512 + tid] = bf2f(A1[(b * 64 + iblk * 4 + 2 + p) * 256 + l]);
    }
    asm volatile("s_waitcnt lgkmcnt(0)" ::: "memory");
    __builtin_amdgcn_sched_barrier(0);
    __builtin_amdgcn_s_barrier();

    // ---- build X1 (swizzled): X1[p*64+j][l] = relu(a1[p][l] + A2[b,j][l])
    const ushort* A2b = A2 + b * 64 * 256;
    #pragma unroll 4
    for (int p8 = 0; p8 < 16; ++p8) {
        int task = p8 * 512 + tid;
        int row = task >> 5, l0 = (task & 31) << 3;
        int j = row & 63, pr = row >> 6;
        uint4 v = *(const uint4*)(A2b + j * 256 + l0);
        const float* av = a1s + pr * 256 + l0;
        uint vv[4] = {v.x, v.y, v.z, v.w}, ov[4];
        #pragma unroll
        for (int qq = 0; qq < 4; ++qq) {
            float f0 = av[2 * qq]     + bf2f((ushort)(vv[qq] & 0xFFFFu));
            float f1 = av[2 * qq + 1] + bf2f((ushort)(vv[qq] >> 16));
            ov[qq] = cvtpk(fmaxf(f0, 0.f), fmaxf(f1, 0.f));
        }
        *(uint4*)&lds_x[row * 256 + (l0 ^ ((row & 7) << 3))] =
            make_uint4(ov[0], ov[1], ov[2], ov[3]);
    }
    asm volatile("s_waitcnt lgkmcnt(0)" ::: "memory");
    __builtin_amdgcn_sched_barrier(0);
    __builtin_amdgcn_s_barrier();

    // ---- prologue: wbuf[0] <- chunk 0; issue chunk 1
    asm volatile("s_waitcnt vmcnt(0)" ::: "memory");
    __builtin_amdgcn_sched_barrier(0);
    {
        uint4* wd = (uint4*)lds_w[0];
        wd[tid] = rbuf0; wd[512 + tid] = rbuf1;
        rbuf0 = wsrc[1024 + tid];
        rbuf1 = wsrc[1024 + 512 + tid];
    }
    asm volatile("s_waitcnt lgkmcnt(0)" ::: "memory");
    __builtin_amdgcn_sched_barrier(0);
    __builtin_amdgcn_s_barrier();

    int q = 0;   // linear chunk index li*8+kc
    #pragma unroll 1
    for (int li = 0; li < 3; ++li) {
        const float* bias = (li == 0) ? b2 : (li == 1) ? b3 : b4;
        f32x4 bias4[4];
        #pragma unroll
        for (int ct = 0; ct < 4; ++ct)
            bias4[ct] = *(const f32x4*)(bias + col0 + ct * 16 + lg * 4);
        f32x4 acc[8][4];
        #pragma unroll
        for (int rt = 0; rt < 8; ++rt)
            #pragma unroll
            for (int ct = 0; ct < 4; ++ct)
                acc[rt][ct] = (f32x4){0.f, 0.f, 0.f, 0.f};

        #pragma unroll 1
        for (int kc = 0; kc < 8; ++kc, ++q) {
            const ushort* wb = lds_w[q & 1];
            bf16x8 xb[8];
            #pragma unroll
            for (int rt = 0; rt < 8; ++rt) {
                int row = wrow0 + rt * 16 + l15;
                xb[rt] = *(const bf16x8*)
                    &lds_x[row * 256 + ((kc * 32 + lg * 8) ^ ((row & 7) << 3))];
            }
            __builtin_amdgcn_s_setprio(1);
            #pragma unroll
            for (int ct = 0; ct < 4; ++ct) {
                int col = col0 + ct * 16 + l15;
                bf16x8 wa = *(const bf16x8*)
                    &wb[col * 32 + ((lg ^ ((col >> 1) & 3)) << 3)];
                #pragma unroll
                for (int rt = 0; rt < 8; ++rt)
                    acc[rt][ct] = __builtin_amdgcn_mfma_f32_16x16x32_bf16(
                        wa, xb[rt], acc[rt][ct], 0, 0, 0);
            }
            __builtin_amdgcn_s_setprio(0);
            // ---- stage chunk q+1 into the other buffer; issue q+2; ONE barrier
            if (q < 23) {
                asm volatile("s_waitcnt vmcnt(0)" ::: "memory");  // rbuf landed (1 chunk old)
                __builtin_amdgcn_sched_barrier(0);
                uint4* wd = (uint4*)lds_w[(q + 1) & 1];
                wd[tid] = rbuf0; wd[512 + tid] = rbuf1;
                if (q < 22) {
                    rbuf0 = wsrc[(q + 2) * 1024 + tid];
                    rbuf1 = wsrc[(q + 2) * 1024 + 512 + tid];
                }
                asm volatile("s_waitcnt lgkmcnt(0)" ::: "memory");
                __builtin_amdgcn_sched_barrier(0);
            }
            __builtin_amdgcn_s_barrier();
        }

        if (li < 2) {
            // all xb reads done (pre-barrier in each chunk) -> overwrite lds_x
            #pragma unroll
            for (int rt = 0; rt < 8; ++rt) {
                int row = wrow0 + rt * 16 + l15;
                int sw = (row & 7) << 3;
                #pragma unroll
                for (int ct = 0; ct < 4; ++ct) {
                    f32x4 a = acc[rt][ct];
                    f32x4 bv = bias4[ct];
                    uint2 pk;
                    pk.x = cvtpk(fmaxf(a[0] + bv[0], 0.f), fmaxf(a[1] + bv[1], 0.f));
                    pk.y = cvtpk(fmaxf(a[2] + bv[2], 0.f), fmaxf(a[3] + bv[3], 0.f));
                    *(uint2*)&lds_x[row * 256 + ((col0 + ct * 16 + lg * 4) ^ sw)] = pk;
                }
            }
            asm volatile("s_waitcnt lgkmcnt(0)" ::: "memory");
            __builtin_amdgcn_sched_barrier(0);
            __builtin_amdgcn_s_barrier();
        } else {
            // ---- reduce: per wave, 2 pairs x 64 rows each; deterministic
            #pragma unroll
            for (int ct = 0; ct < 4; ++ct) {
                f32x4 bv = bias4[ct];
                f32x4 s0 = {0.f, 0.f, 0.f, 0.f}, s1 = {0.f, 0.f, 0.f, 0.f};
                #pragma unroll
                for (int rt = 0; rt < 4; ++rt) {
                    f32x4 a = acc[rt][ct];
                    s0[0] += fmaxf(a[0] + bv[0], 0.f); s0[1] += fmaxf(a[1] + bv[1], 0.f);
                    s0[2] += fmaxf(a[2] + bv[2], 0.f); s0[3] += fmaxf(a[3] + bv[3], 0.f);
                }
                #pragma unroll
                for (int rt = 4; rt < 8; ++rt) {
                    f32x4 a = acc[rt][ct];
                    s1[0] += fmaxf(a[0] + bv[0], 0.f); s1[1] += fmaxf(a[1] + bv[1], 0.f);
                    s1[2] += fmaxf(a[2] + bv[2], 0.f); s1[3] += fmaxf(a[3] + bv[3], 0.f);
                }
                #pragma unroll
                for (int m = 1; m < 16; m <<= 1) {
                    #pragma unroll
                    for (int r = 0; r < 4; ++r) {
                        s0[r] += __shfl_xor(s0[r], m, 64);
                        s1[r] += __shfl_xor(s1[r], m, 64);
                    }
                }
                if (l15 == 0) {
                    int prow = b * 64 + iblk * 4 + (wv & 1) * 2;
                    float4 o0 = {s0[0], s0[1], s0[2], s0[3]};
                    float4 o1 = {s1[0], s1[1], s1[2], s1[3]};
                    *(float4*)&partial[(prow    ) * 256 + col0 + ct * 16 + lg * 4] = o0;
                    *(float4*)&partial[(prow + 1) * 256 + col0 + ct * 16 + lg * 4] = o1;
                }
            }
        }
    }
}

// ---------------- kernel 6: g_out[b][col] = sum_i partial[(b,i)][col]
__global__ void kR(const float* __restrict__ partial, float* __restrict__ gout)
{
    int b = blockIdx.x, col = threadIdx.x;     // block 256
    float s = 0.f;
    for (int i = 0; i < 64; ++i) s += partial[(b * 64 + i) * 256 + col];
    gout[b * 256 + col] = s;
}

// ---------------- kernel 7: f-network
__global__ void kF(const float* __restrict__ gout,
                   const float* __restrict__ f_w1, const float* __restrict__ f_b1,
                   const float* __restrict__ f_w2, const float* __restrict__ f_b2,
                   const float* __restrict__ f_w3, const float* __restrict__ f_b3,
                   float* __restrict__ out)
{
    __shared__ float g[256], y1[256], y2[256];
    int b = blockIdx.x, t = threadIdx.x;       // block 256
    g[t] = gout[b * 256 + t];
    __syncthreads();
    float acc = f_b1[t];
    for (int k = 0; k < 256; ++k) acc += g[k] * f_w1[k * 256 + t];
    y1[t] = fmaxf(acc, 0.f);
    __syncthreads();
    acc = f_b2[t];
    for (int k = 0; k < 256; ++k) acc += y1[k] * f_w2[k * 256 + t];
    y2[t] = fmaxf(acc, 0.f);
    __syncthreads();
    if (t < 100) {
        float o = f_b3[t];
        for (int k = 0; k < 256; ++k) o += y2[k] * f_w3[k * 100 + t];
        out[b * 100 + t] = o;
    }
}

extern "C" void kernel_launch(void* const* d_in, const int* in_sizes, int n_in,
                              void* d_out, int out_size, void* d_ws, size_t ws_size,
                              hipStream_t stream)
{
    const float* box_feats = (const float*)d_in[0];
    const float* emb   = (const float*)d_in[1];
    const float* w_ih  = (const float*)d_in[2];
    const float* w_hh  = (const float*)d_in[3];
    const float* b_ih  = (const float*)d_in[4];
    const float* b_hh  = (const float*)d_in[5];
    const float* g_w1  = (const float*)d_in[6];
    const float* g_b1  = (const float*)d_in[7];
    const float* g_w2  = (const float*)d_in[8];
    const float* g_b2  = (const float*)d_in[9];
    const float* g_w3  = (const float*)d_in[10];
    const float* g_b3  = (const float*)d_in[11];
    const float* g_w4  = (const float*)d_in[12];
    const float* g_b4  = (const float*)d_in[13];
    const float* f_w1  = (const float*)d_in[14];
    const float* f_b1  = (const float*)d_in[15];
    const float* f_w2  = (const float*)d_in[16];
    const float* f_b2  = (const float*)d_in[17];
    const float* f_w3  = (const float*)d_in[18];
    const float* f_b3  = (const float*)d_in[19];
    const int* q_feats = (const int*)d_in[20];
    const int* q_lens  = (const int*)d_in[21];
    float* out = (float*)d_out;

    char* ws = (char*)d_ws;
    float*  P    = (float*) (ws + 0);          //  96*512*4      = 196608
    float*  Wq   = (float*) (ws + 196608);     // 128*256*4      = 131072
    ushort* A1   = (ushort*)(ws + 327680);     // 8192*256*2     = 4194304
    ushort* A2   = (ushort*)(ws + 4521984);    // 8192*256*2     = 4194304
    ushort* Wst  = (ushort*)(ws + 8716288);    // 3*65536*2      = 393216
    float*  part = (float*) (ws + 9109504);    // 8192*256*4     = 8388608
    float*  gout = (float*) (ws + 17498112);   // 128*256*4      = 131072

    hipLaunchKernelGGL(kP,    dim3(96),   dim3(512), 0, stream, emb, w_ih, b_ih, P);
    hipLaunchKernelGGL(kW,    dim3(24),   dim3(256), 0, stream, g_w2, g_w3, g_w4, Wst);
    hipLaunchKernelGGL(kLSTM, dim3(128),  dim3(256), 0, stream, P, w_hh, b_hh, g_w1, g_b1, q_feats, q_lens, Wq);
    hipLaunchKernelGGL(kA,    dim3(128),  dim3(256), 0, stream, box_feats, g_w1, Wq, A1, A2);
    hipLaunchKernelGGL(kD,    dim3(2048), dim3(512), 0, stream, A1, A2, Wst, g_b2, g_b3, g_b4, part);
    hipLaunchKernelGGL(kR,    dim3(128),  dim3(256), 0, stream, part, gout);
    hipLaunchKernelGGL(kF,    dim3(128),  dim3(256), 0, stream, gout, f_w1, f_b1, f_w2, f_b2, f_w3, f_b3, out);
}